// Round 7
// baseline (1216.923 us; speedup 1.0000x reference)
//
#include <hip/hip_runtime.h>
#include <hip/hip_bf16.h>

#define BATCH 2
#define SEQ 2048
#define EMBED 1024
#define NHEADS 16
#define HDIM 64

// INSTRUMENTATION ROUND: repeat compute loops 4x (numerics-invariant) so that
// per-kernel durations become visible in the top-5 dispatch profile, and
// S = (T - 766)/3 decomposes the kernel budget. Revert next round.
#define REP 4

typedef __hip_bfloat16 bf16;
typedef __attribute__((ext_vector_type(8))) short bf16x8;   // 8 bf16 (4 VGPRs)
typedef __attribute__((ext_vector_type(4))) short bf16x4;
typedef __attribute__((ext_vector_type(4))) float f32x4;

typedef const __attribute__((address_space(1))) void* gaddr_t;
typedef __attribute__((address_space(3))) void* laddr_t;

__device__ __forceinline__ bf16x8 lds_frag8(const bf16* p) {
    const bf16x4 a = *(const bf16x4*)p;
    const bf16x4 b = *(const bf16x4*)(p + 4);
    return __builtin_shufflevector(a, b, 0, 1, 2, 3, 4, 5, 6, 7);
}

// fused f32 -> bf16 (RNE) for x, qkv_w, proj_w in one launch
__global__ __launch_bounds__(256)
void f2b_all(const float* __restrict__ s0, bf16* __restrict__ d0, int n0,
             const float* __restrict__ s1, bf16* __restrict__ d1, int n1,
             const float* __restrict__ s2, bf16* __restrict__ d2, int n2)
{
    int i = blockIdx.x * 256 + threadIdx.x;
    const float* s; bf16* d;
    if (i < n0)                { s = s0; d = d0; }
    else if ((i -= n0) < n1)   { s = s1; d = d1; }
    else if ((i -= n1) < n2)   { s = s2; d = d2; }
    else return;
    const float4 v = ((const float4*)s)[i];
    union { ushort4 u4; bf16 h[4]; } o;
    o.h[0] = __float2bfloat16(v.x);
    o.h[1] = __float2bfloat16(v.y);
    o.h[2] = __float2bfloat16(v.z);
    o.h[3] = __float2bfloat16(v.w);
    ((ushort4*)d)[i] = o.u4;
}

// C = A(M,K) @ B(N,K)^T + bias(N), bf16 in, fp32 accum, f32 bias.
// MODE 0: C = float*, row-major (M,N).
// MODE 1: QKV scatter: Q,K -> [b][h][s][d]; V -> TRANSPOSED [b][h][d][s].
template<int MODE>
__global__ __launch_bounds__(256)
void gemm_bt(const bf16* __restrict__ A, const bf16* __restrict__ B,
             const float* __restrict__ bias, void* __restrict__ Cv,
             int M, int N, int K)
{
    __shared__ __align__(16) bf16 lA[128 * 32];
    __shared__ __align__(16) bf16 lB[128 * 32];
    const int tid  = threadIdx.x;
    const int bn   = blockIdx.x, bm = blockIdx.y;
    const int wave = tid >> 6, lane = tid & 63;
    const int wm   = (wave >> 1) << 6, wn = (wave & 1) << 6;   // 2x2 waves of 64x64
    const int quad = lane >> 4, l16 = lane & 15;

    f32x4 acc[4][4] = {};

    for (int rep = 0; rep < REP; ++rep)
    for (int kt = 0; kt < K; kt += 32) {
        __syncthreads();
        #pragma unroll
        for (int i = 0; i < 2; ++i) {
            const int c = tid + (i << 8);            // 512 16B chunks per 128x32 tile
            const int r = c >> 2, kc = (c & 3) << 3; // row, k-col(8 bf16)
            const bf16* gA = A + (long)(bm * 128 + r) * K + (kt + kc);
            const bf16* gB = B + (long)(bn * 128 + r) * K + (kt + kc);
            __builtin_amdgcn_global_load_lds((gaddr_t)gA, (laddr_t)&lA[c << 3], 16, 0, 0);
            __builtin_amdgcn_global_load_lds((gaddr_t)gB, (laddr_t)&lB[c << 3], 16, 0, 0);
        }
        __syncthreads();

        bf16x8 af[4], bfr[4];
        #pragma unroll
        for (int t = 0; t < 4; ++t) {
            af[t]  = *(const bf16x8*)&lA[(wm + t * 16 + l16) * 32 + quad * 8];
            bfr[t] = *(const bf16x8*)&lB[(wn + t * 16 + l16) * 32 + quad * 8];
        }
        #pragma unroll
        for (int tm = 0; tm < 4; ++tm)
            #pragma unroll
            for (int tn = 0; tn < 4; ++tn)
                acc[tm][tn] = __builtin_amdgcn_mfma_f32_16x16x32_bf16(
                    af[tm], bfr[tn], acc[tm][tn], 0, 0, 0);
    }

    const float rscale = 1.0f / REP;
    #pragma unroll
    for (int tm = 0; tm < 4; ++tm) {
        #pragma unroll
        for (int tn = 0; tn < 4; ++tn) {
            const int gn = bn * 128 + wn + tn * 16 + l16;
            const float bv = bias[gn];
            if (MODE == 0) {
                #pragma unroll
                for (int r = 0; r < 4; ++r) {
                    const int gm = bm * 128 + wm + tm * 16 + quad * 4 + r;
                    ((float*)Cv)[(long)gm * N + gn] = acc[tm][tn][r] * rscale + bv;
                }
            } else {
                const int part = gn >> 10, h = (gn >> 6) & (NHEADS - 1), d = gn & (HDIM - 1);
                const int gm0 = bm * 128 + wm + tm * 16 + quad * 4;   // 4 consecutive rows
                const int b = gm0 >> 11, s0 = gm0 & (SEQ - 1);
                if (part == 2) {
                    // V transposed: [b][h][d][s], 4 consecutive s per lane -> short4
                    union { ushort4 u4; bf16 hv[4]; } o;
                    #pragma unroll
                    for (int r = 0; r < 4; ++r) o.hv[r] = __float2bfloat16(acc[tm][tn][r] * rscale + bv);
                    const long off = ((((long)2 * BATCH + b) * NHEADS + h) * HDIM + d) * SEQ + s0;
                    *(ushort4*)((bf16*)Cv + off) = o.u4;
                } else {
                    #pragma unroll
                    for (int r = 0; r < 4; ++r) {
                        const long off = ((((long)part * BATCH + b) * NHEADS + h) * SEQ + (s0 + r)) * HDIM + d;
                        ((bf16*)Cv)[off] = __float2bfloat16(acc[tm][tn][r] * rscale + bv);
                    }
                }
            }
        }
    }
}

// Barrier-free flash attention: wave = 32 queries, K/V read directly from
// global (L2-hot), V pre-transposed [b][h][d][s] so the PV B-fragment is a
// coalesced int4 load. LDS only for the wave-private P C->A relayout.
__global__ __launch_bounds__(256)
void attn_nf(const bf16* __restrict__ Q, const bf16* __restrict__ K,
             const bf16* __restrict__ Vt, bf16* __restrict__ O)
{
    __shared__ __align__(16) bf16 pS[4 * 32 * 68];   // per-wave P slab

    const int tid  = threadIdx.x;
    const int wave = tid >> 6, lane = tid & 63;
    const int quad = lane >> 4, l15 = lane & 15;
    const int bh   = blockIdx.y;
    const int qg   = (15 - blockIdx.x) * 4 + wave;   // q-group of 32 (heaviest first)
    const int qw0  = qg * 32;

    const bf16* Qb  = Q  + (long)bh * SEQ * HDIM;
    const bf16* Kb  = K  + (long)bh * SEQ * HDIM;
    const bf16* Vtb = Vt + (long)bh * HDIM * SEQ;
    bf16* pW = pS + wave * 32 * 68;

    // Q A-frags [mt][c]: A[m=l15][k=c*32+quad*8+j]
    bf16x8 qf[2][2];
    #pragma unroll
    for (int mt = 0; mt < 2; ++mt)
        #pragma unroll
        for (int c = 0; c < 2; ++c) {
            union { int4 i; bf16x8 v; } u;
            u.i = *(const int4*)(Qb + (long)(qw0 + mt * 16 + l15) * HDIM + c * 32 + quad * 8);
            qf[mt][c] = u.v;
        }

    f32x4 acc[2][4] = {};          // O accumulator (C layout)
    float lsum[8] = {};            // per-lane partial denominators

    const int nkt = (qw0 >> 6) + 1;                      // tiles covering keys <= qw0+31
    const float sc = 0.125f * 1.44269504088896340736f;   // D^-0.5 * log2(e)

    // REP x repeat: acc and lsum both scale by REP -> O = acc/lsum invariant.
    for (int rep = 0; rep < REP; ++rep)
    for (int t = 0; t < nkt; ++t) {
        const int kb = t * 64;

        // --- S = Q K^T: kf = B[n=key][k=d], coalesced from [s][d] layout ---
        f32x4 s[2][4] = {};
        #pragma unroll
        for (int c = 0; c < 2; ++c) {
            #pragma unroll
            for (int nt = 0; nt < 4; ++nt) {
                union { int4 i; bf16x8 v; } u;
                u.i = *(const int4*)(Kb + (long)(kb + nt * 16 + l15) * HDIM + c * 32 + quad * 8);
                #pragma unroll
                for (int mt = 0; mt < 2; ++mt)
                    s[mt][nt] = __builtin_amdgcn_mfma_f32_16x16x32_bf16(
                        qf[mt][c], u.v, s[mt][nt], 0, 0, 0);
            }
        }

        // --- softmax (fixed-reference) + P to wave-private LDS ---
        #pragma unroll
        for (int mt = 0; mt < 2; ++mt)
            #pragma unroll
            for (int nt = 0; nt < 4; ++nt)
                #pragma unroll
                for (int r = 0; r < 4; ++r) {
                    const int rl = mt * 16 + quad * 4 + r;       // local q row
                    const int cl = nt * 16 + l15;                // local key col
                    const float p = ((kb + cl) <= (qw0 + rl))
                        ? __builtin_amdgcn_exp2f(s[mt][nt][r] * sc) : 0.f;
                    lsum[mt * 4 + r] += p;
                    pW[rl * 68 + cl] = __float2bfloat16(p);
                }

        // --- O += P V: vf = B[n=d][k=key], coalesced from V^T [d][s] layout ---
        #pragma unroll
        for (int c = 0; c < 2; ++c) {
            bf16x8 pf[2];
            #pragma unroll
            for (int mt = 0; mt < 2; ++mt)
                pf[mt] = lds_frag8(&pW[(mt * 16 + l15) * 68 + c * 32 + quad * 8]);
            #pragma unroll
            for (int nt = 0; nt < 4; ++nt) {
                union { int4 i; bf16x8 v; } u;
                u.i = *(const int4*)(Vtb + (long)(nt * 16 + l15) * SEQ + kb + c * 32 + quad * 8);
                #pragma unroll
                for (int mt = 0; mt < 2; ++mt)
                    acc[mt][nt] = __builtin_amdgcn_mfma_f32_16x16x32_bf16(
                        pf[mt], u.v, acc[mt][nt], 0, 0, 0);
            }
        }
    }

    // reduce lsum across the 16 key-lanes of each quad row-group
    #pragma unroll
    for (int i = 0; i < 8; ++i) {
        #pragma unroll
        for (int m = 1; m < 16; m <<= 1) lsum[i] += __shfl_xor(lsum[i], m, 64);
        lsum[i] = 1.f / lsum[i];
    }

    const int b = bh >> 4, h = bh & 15;
    #pragma unroll
    for (int mt = 0; mt < 2; ++mt)
        #pragma unroll
        for (int r = 0; r < 4; ++r) {
            const int rl = mt * 16 + quad * 4 + r;
            bf16* orow = O + ((long)b * SEQ + (qw0 + rl)) * EMBED + h * HDIM;
            const float inv = lsum[mt * 4 + r];
            #pragma unroll
            for (int nt = 0; nt < 4; ++nt)
                orow[nt * 16 + l15] = __float2bfloat16(acc[mt][nt][r] * inv);
        }
}

extern "C" void kernel_launch(void* const* d_in, const int* in_sizes, int n_in,
                              void* d_out, int out_size, void* d_ws, size_t ws_size,
                              hipStream_t stream)
{
    const float* x      = (const float*)d_in[0];
    // d_in[1] = mask: causal by construction, computed analytically — unused.
    const float* qkv_w  = (const float*)d_in[2];
    const float* qkv_b  = (const float*)d_in[3];
    const float* proj_w = (const float*)d_in[4];
    const float* proj_b = (const float*)d_in[5];
    float* out = (float*)d_out;

    const long nX  = (long)BATCH * SEQ * EMBED;     // 4,194,304
    const long nQW = 3L * EMBED * EMBED;            // 3,145,728
    const long nPW = (long)EMBED * EMBED;           // 1,048,576
    const long per = (long)BATCH * NHEADS * SEQ * HDIM;  // 4,194,304

    bf16* xw  = (bf16*)d_ws;          // x in bf16
    bf16* qwm = xw + nX;              // qkv_w bf16
    bf16* pwm = qwm + nQW;            // proj_w bf16
    bf16* qw  = pwm + nPW;            // Q [b][h][s][d]
    bf16* kw  = qw + per;             // K [b][h][s][d]
    bf16* vw  = kw + per;             // V TRANSPOSED [b][h][d][s]
    bf16* att = vw + per;             // (B*S, E) bf16 row-major

    // 0) f32 -> bf16 conversions (single launch)
    const int n0 = (int)(nX / 4), n1 = (int)(nQW / 4), n2 = (int)(nPW / 4);
    f2b_all<<<(n0 + n1 + n2 + 255) / 256, 256, 0, stream>>>(
        x, xw, n0, qkv_w, qwm, n1, proj_w, pwm, n2);

    // 1) QKV: (B*S,E) @ (3E,E)^T + b, scattered (V transposed)
    gemm_bt<1><<<dim3(3 * EMBED / 128, BATCH * SEQ / 128), 256, 0, stream>>>(
        xw, qwm, qkv_b, qw, BATCH * SEQ, 3 * EMBED, EMBED);

    // 2) barrier-free causal attention -> att (B,S,E) bf16
    attn_nf<<<dim3(16, BATCH * NHEADS), 256, 0, stream>>>(qw, kw, vw, att);

    // 3) out(f32) = att @ proj_w^T + proj_b
    gemm_bt<0><<<dim3(EMBED / 128, BATCH * SEQ / 128), 256, 0, stream>>>(
        att, pwm, proj_b, out, BATCH * SEQ, EMBED, EMBED);
}

// Round 8
// 723.884 us; speedup vs baseline: 1.6811x; 1.6811x over previous
//
#include <hip/hip_runtime.h>
#include <hip/hip_bf16.h>

#define BATCH 2
#define SEQ 2048
#define EMBED 1024
#define NHEADS 16
#define HDIM 64

typedef __hip_bfloat16 bf16;
typedef __attribute__((ext_vector_type(8))) short bf16x8;   // 8 bf16 (4 VGPRs)
typedef __attribute__((ext_vector_type(4))) short bf16x4;
typedef __attribute__((ext_vector_type(4))) float f32x4;

typedef const __attribute__((address_space(1))) void* gaddr_t;
typedef __attribute__((address_space(3))) void* laddr_t;

__device__ __forceinline__ bf16x8 lds_frag8(const bf16* p) {
    const bf16x4 a = *(const bf16x4*)p;
    const bf16x4 b = *(const bf16x4*)(p + 4);
    return __builtin_shufflevector(a, b, 0, 1, 2, 3, 4, 5, 6, 7);
}

// fused f32 -> bf16 (RNE) for x, qkv_w, proj_w in one launch
__global__ __launch_bounds__(256)
void f2b_all(const float* __restrict__ s0, bf16* __restrict__ d0, int n0,
             const float* __restrict__ s1, bf16* __restrict__ d1, int n1,
             const float* __restrict__ s2, bf16* __restrict__ d2, int n2)
{
    int i = blockIdx.x * 256 + threadIdx.x;
    const float* s; bf16* d;
    if (i < n0)                { s = s0; d = d0; }
    else if ((i -= n0) < n1)   { s = s1; d = d1; }
    else if ((i -= n1) < n2)   { s = s2; d = d2; }
    else return;
    const float4 v = ((const float4*)s)[i];
    union { ushort4 u4; bf16 h[4]; } o;
    o.h[0] = __float2bfloat16(v.x);
    o.h[1] = __float2bfloat16(v.y);
    o.h[2] = __float2bfloat16(v.z);
    o.h[3] = __float2bfloat16(v.w);
    ((ushort4*)d)[i] = o.u4;
}

// C = A(M,K) @ B(N,K)^T + bias(N), bf16 in, fp32 accum, f32 bias.
// MODE 0: C = float*, row-major (M,N).
// MODE 1: QKV scatter: Q,K -> [b][h][s][d]; V -> TRANSPOSED [b][h][d][s].
template<int MODE>
__global__ __launch_bounds__(256)
void gemm_bt(const bf16* __restrict__ A, const bf16* __restrict__ B,
             const float* __restrict__ bias, void* __restrict__ Cv,
             int M, int N, int K)
{
    __shared__ __align__(16) bf16 lA[128 * 32];
    __shared__ __align__(16) bf16 lB[128 * 32];
    const int tid  = threadIdx.x;
    const int bn   = blockIdx.x, bm = blockIdx.y;
    const int wave = tid >> 6, lane = tid & 63;
    const int wm   = (wave >> 1) << 6, wn = (wave & 1) << 6;   // 2x2 waves of 64x64
    const int quad = lane >> 4, l16 = lane & 15;

    f32x4 acc[4][4] = {};

    for (int kt = 0; kt < K; kt += 32) {
        __syncthreads();
        #pragma unroll
        for (int i = 0; i < 2; ++i) {
            const int c = tid + (i << 8);            // 512 16B chunks per 128x32 tile
            const int r = c >> 2, kc = (c & 3) << 3; // row, k-col(8 bf16)
            const bf16* gA = A + (long)(bm * 128 + r) * K + (kt + kc);
            const bf16* gB = B + (long)(bn * 128 + r) * K + (kt + kc);
            __builtin_amdgcn_global_load_lds((gaddr_t)gA, (laddr_t)&lA[c << 3], 16, 0, 0);
            __builtin_amdgcn_global_load_lds((gaddr_t)gB, (laddr_t)&lB[c << 3], 16, 0, 0);
        }
        __syncthreads();

        bf16x8 af[4], bfr[4];
        #pragma unroll
        for (int t = 0; t < 4; ++t) {
            af[t]  = *(const bf16x8*)&lA[(wm + t * 16 + l16) * 32 + quad * 8];
            bfr[t] = *(const bf16x8*)&lB[(wn + t * 16 + l16) * 32 + quad * 8];
        }
        #pragma unroll
        for (int tm = 0; tm < 4; ++tm)
            #pragma unroll
            for (int tn = 0; tn < 4; ++tn)
                acc[tm][tn] = __builtin_amdgcn_mfma_f32_16x16x32_bf16(
                    af[tm], bfr[tn], acc[tm][tn], 0, 0, 0);
    }

    #pragma unroll
    for (int tm = 0; tm < 4; ++tm) {
        #pragma unroll
        for (int tn = 0; tn < 4; ++tn) {
            const int gn = bn * 128 + wn + tn * 16 + l16;
            const float bv = bias[gn];
            if (MODE == 0) {
                #pragma unroll
                for (int r = 0; r < 4; ++r) {
                    const int gm = bm * 128 + wm + tm * 16 + quad * 4 + r;
                    ((float*)Cv)[(long)gm * N + gn] = acc[tm][tn][r] + bv;
                }
            } else {
                const int part = gn >> 10, h = (gn >> 6) & (NHEADS - 1), d = gn & (HDIM - 1);
                const int gm0 = bm * 128 + wm + tm * 16 + quad * 4;   // 4 consecutive rows
                const int b = gm0 >> 11, s0 = gm0 & (SEQ - 1);
                if (part == 2) {
                    // V transposed: [b][h][d][s], 4 consecutive s per lane -> short4
                    union { ushort4 u4; bf16 hv[4]; } o;
                    #pragma unroll
                    for (int r = 0; r < 4; ++r) o.hv[r] = __float2bfloat16(acc[tm][tn][r] + bv);
                    const long off = ((((long)2 * BATCH + b) * NHEADS + h) * HDIM + d) * SEQ + s0;
                    *(ushort4*)((bf16*)Cv + off) = o.u4;
                } else {
                    #pragma unroll
                    for (int r = 0; r < 4; ++r) {
                        const long off = ((((long)part * BATCH + b) * NHEADS + h) * SEQ + (s0 + r)) * HDIM + d;
                        ((bf16*)Cv)[off] = __float2bfloat16(acc[tm][tn][r] + bv);
                    }
                }
            }
        }
    }
}

// Barrier-free flash attention, key-split x2 for TLP (4096 waves = 4/SIMD)
// and XCD-affine grid (blockIdx.x = bh -> flat%8 = bh%8 -> one XCD per bh).
// Wave = 32 queries; K/V direct from global (L2-hot); V^T for coalesced PV.
// Emits unnormalized f32 O-partials + partial denominators.
__global__ __launch_bounds__(256)
void attn_nf(const bf16* __restrict__ Q, const bf16* __restrict__ K,
             const bf16* __restrict__ Vt, float* __restrict__ Op,
             float* __restrict__ lp)
{
    __shared__ __align__(16) bf16 pS[4 * 32 * 68];   // per-wave P slab

    const int tid  = threadIdx.x;
    const int wave = tid >> 6, lane = tid & 63;
    const int quad = lane >> 4, l15 = lane & 15;
    const int bh   = blockIdx.x;                     // XCD affinity: flat%8 = bh%8
    const int half = blockIdx.y >> 4;
    const int qidx = blockIdx.y & 15;
    const int qg   = (15 - qidx) * 4 + wave;         // heaviest first
    const int qw0  = qg * 32;

    const bf16* Qb  = Q  + (long)bh * SEQ * HDIM;
    const bf16* Kb  = K  + (long)bh * SEQ * HDIM;
    const bf16* Vtb = Vt + (long)bh * HDIM * SEQ;
    bf16* pW = pS + wave * 32 * 68;

    // Q A-frags [mt][c]: A[m=l15][k=c*32+quad*8+j]
    bf16x8 qf[2][2];
    #pragma unroll
    for (int mt = 0; mt < 2; ++mt)
        #pragma unroll
        for (int c = 0; c < 2; ++c) {
            union { int4 i; bf16x8 v; } u;
            u.i = *(const int4*)(Qb + (long)(qw0 + mt * 16 + l15) * HDIM + c * 32 + quad * 8);
            qf[mt][c] = u.v;
        }

    f32x4 acc[2][4] = {};          // unnormalized O (C layout)
    float lsum[8] = {};            // per-lane partial denominators

    const int nkt = (qw0 >> 6) + 1;                      // full tile count for this wave
    const float sc = 0.125f * 1.44269504088896340736f;   // D^-0.5 * log2(e)

    for (int t = half; t < nkt; t += 2) {
        const int kb = t * 64;

        // --- S = Q K^T: kf = B[n=key][k=d], coalesced from [s][d] layout ---
        f32x4 s[2][4] = {};
        #pragma unroll
        for (int c = 0; c < 2; ++c) {
            #pragma unroll
            for (int nt = 0; nt < 4; ++nt) {
                union { int4 i; bf16x8 v; } u;
                u.i = *(const int4*)(Kb + (long)(kb + nt * 16 + l15) * HDIM + c * 32 + quad * 8);
                #pragma unroll
                for (int mt = 0; mt < 2; ++mt)
                    s[mt][nt] = __builtin_amdgcn_mfma_f32_16x16x32_bf16(
                        qf[mt][c], u.v, s[mt][nt], 0, 0, 0);
            }
        }

        // --- softmax (fixed-reference) + P to wave-private LDS ---
        #pragma unroll
        for (int mt = 0; mt < 2; ++mt)
            #pragma unroll
            for (int nt = 0; nt < 4; ++nt)
                #pragma unroll
                for (int r = 0; r < 4; ++r) {
                    const int rl = mt * 16 + quad * 4 + r;       // local q row
                    const int cl = nt * 16 + l15;                // local key col
                    const float p = ((kb + cl) <= (qw0 + rl))
                        ? __builtin_amdgcn_exp2f(s[mt][nt][r] * sc) : 0.f;
                    lsum[mt * 4 + r] += p;
                    pW[rl * 68 + cl] = __float2bfloat16(p);
                }

        // --- O += P V: vf = B[n=d][k=key], coalesced from V^T [d][s] layout ---
        #pragma unroll
        for (int c = 0; c < 2; ++c) {
            bf16x8 pf[2];
            #pragma unroll
            for (int mt = 0; mt < 2; ++mt)
                pf[mt] = lds_frag8(&pW[(mt * 16 + l15) * 68 + c * 32 + quad * 8]);
            #pragma unroll
            for (int nt = 0; nt < 4; ++nt) {
                union { int4 i; bf16x8 v; } u;
                u.i = *(const int4*)(Vtb + (long)(nt * 16 + l15) * SEQ + kb + c * 32 + quad * 8);
                #pragma unroll
                for (int mt = 0; mt < 2; ++mt)
                    acc[mt][nt] = __builtin_amdgcn_mfma_f32_16x16x32_bf16(
                        pf[mt], u.v, acc[mt][nt], 0, 0, 0);
            }
        }
    }

    // reduce lsum across the 16 key-lanes of each quad row-group
    #pragma unroll
    for (int i = 0; i < 8; ++i)
        #pragma unroll
        for (int m = 1; m < 16; m <<= 1) lsum[i] += __shfl_xor(lsum[i], m, 64);

    const long halfO = (long)BATCH * NHEADS * SEQ * HDIM;
    float* Oh = Op + half * halfO + ((long)bh * SEQ) * HDIM;
    float* lh = lp + half * (BATCH * NHEADS * SEQ) + bh * SEQ;
    #pragma unroll
    for (int mt = 0; mt < 2; ++mt)
        #pragma unroll
        for (int r = 0; r < 4; ++r) {
            const int rl = mt * 16 + quad * 4 + r;
            float* orow = Oh + (long)(qw0 + rl) * HDIM;
            #pragma unroll
            for (int nt = 0; nt < 4; ++nt)
                orow[nt * 16 + l15] = acc[mt][nt][r];
            if (l15 == 0) lh[qw0 + rl] = lsum[mt * 4 + r];
        }
}

// att[b][s][h*64+d] = (O0 + O1) / (l0 + l1), f32 -> bf16
__global__ __launch_bounds__(256)
void attn_combine(const float* __restrict__ Op, const float* __restrict__ lp,
                  bf16* __restrict__ att)
{
    const int i = blockIdx.x * 256 + threadIdx.x;      // over [bh][q][d/4]
    const int d4 = i & 15, q = (i >> 4) & (SEQ - 1), bh = i >> 15;
    const long halfO = (long)BATCH * NHEADS * SEQ * HDIM;
    const long rowo  = ((long)bh * SEQ + q) * HDIM;
    const float4 a = ((const float4*)(Op + rowo))[d4];
    const float4 b = ((const float4*)(Op + halfO + rowo))[d4];
    const int li = bh * SEQ + q;
    const float inv = 1.f / (lp[li] + lp[BATCH * NHEADS * SEQ + li]);
    const int bb = bh >> 4, h = bh & 15;
    union { ushort4 u4; bf16 hv[4]; } o;
    o.hv[0] = __float2bfloat16((a.x + b.x) * inv);
    o.hv[1] = __float2bfloat16((a.y + b.y) * inv);
    o.hv[2] = __float2bfloat16((a.z + b.z) * inv);
    o.hv[3] = __float2bfloat16((a.w + b.w) * inv);
    *(ushort4*)(att + ((long)bb * SEQ + q) * EMBED + h * HDIM + d4 * 4) = o.u4;
}

extern "C" void kernel_launch(void* const* d_in, const int* in_sizes, int n_in,
                              void* d_out, int out_size, void* d_ws, size_t ws_size,
                              hipStream_t stream)
{
    const float* x      = (const float*)d_in[0];
    // d_in[1] = mask: causal by construction, computed analytically — unused.
    const float* qkv_w  = (const float*)d_in[2];
    const float* qkv_b  = (const float*)d_in[3];
    const float* proj_w = (const float*)d_in[4];
    const float* proj_b = (const float*)d_in[5];
    float* out = (float*)d_out;

    const long nX  = (long)BATCH * SEQ * EMBED;     // 4,194,304
    const long nQW = 3L * EMBED * EMBED;            // 3,145,728
    const long nPW = (long)EMBED * EMBED;           // 1,048,576
    const long per = (long)BATCH * NHEADS * SEQ * HDIM;  // 4,194,304

    bf16* xw  = (bf16*)d_ws;          // x in bf16
    bf16* qwm = xw + nX;              // qkv_w bf16
    bf16* pwm = qwm + nQW;            // proj_w bf16
    bf16* qw  = pwm + nPW;            // Q [b][h][s][d]
    bf16* kw  = qw + per;             // K [b][h][s][d]
    bf16* vw  = kw + per;             // V TRANSPOSED [b][h][d][s]
    bf16* att = vw + per;             // (B*S, E) bf16 row-major
    float* Op = (float*)(att + per);  // 2 x per f32 (O partials)
    float* lp = Op + 2 * per;         // 2 x B*H*S f32 (l partials)

    // 0) f32 -> bf16 conversions (single launch)
    const int n0 = (int)(nX / 4), n1 = (int)(nQW / 4), n2 = (int)(nPW / 4);
    f2b_all<<<(n0 + n1 + n2 + 255) / 256, 256, 0, stream>>>(
        x, xw, n0, qkv_w, qwm, n1, proj_w, pwm, n2);

    // 1) QKV: (B*S,E) @ (3E,E)^T + b, scattered (V transposed)
    gemm_bt<1><<<dim3(3 * EMBED / 128, BATCH * SEQ / 128), 256, 0, stream>>>(
        xw, qwm, qkv_b, qw, BATCH * SEQ, 3 * EMBED, EMBED);

    // 2) barrier-free causal attention (key-split x2, XCD-affine) + combine
    attn_nf<<<dim3(BATCH * NHEADS, 32), 256, 0, stream>>>(qw, kw, vw, Op, lp);
    attn_combine<<<(int)(per / 4 / 256), 256, 0, stream>>>(Op, lp, att);

    // 3) out(f32) = att @ proj_w^T + proj_b
    gemm_bt<0><<<dim3(EMBED / 128, BATCH * SEQ / 128), 256, 0, stream>>>(
        att, pwm, proj_b, out, BATCH * SEQ, EMBED, EMBED);
}